// Round 2
// baseline (1176.551 us; speedup 1.0000x reference)
//
#include <hip/hip_runtime.h>
#include <math.h>

#define DIM 128
#define BATCH 1048576
#define WT_STRIDE 136   // bf16 elements per row of W^T: 128 + 8 pad
#define VT_STRIDE 132   // f32 stride for staged v columns: %4==0 -> 16B-aligned b128 reads
#define GEMM_GRID 1024  // 4 blocks per CU, fully persistent
#define ROWS_PER_TILE 64                      // 4 waves x 16 rows
#define NTILES (BATCH / ROWS_PER_TILE)        // 16384
#define TILES_PER_BLOCK (NTILES / GEMM_GRID)  // 16 (even -> clean ping-pong)

typedef float f32x4 __attribute__((ext_vector_type(4)));
typedef short bf16x8 __attribute__((ext_vector_type(8)));

// fp32 -> bf16 round-to-nearest-even (bit trick; no NaN inputs here)
__device__ __forceinline__ unsigned short f2bf(float f) {
    unsigned u = __builtin_bit_cast(unsigned, f);
    u += 0x7FFFu + ((u >> 16) & 1u);
    return (unsigned short)(u >> 16);
}

// ---------------------------------------------------------------------------
// Kernel A: build W^T (bf16, padded stride) from the Householder scan.
// Pair-per-row layout: thread t holds Q[r][c0..c0+63], r = t>>1, c0=(t&1)*64.
// All 128 inverse norms are precomputed BEFORE the scan (they don't depend
// on Q) -> the 128-step loop has zero barriers and zero butterflies; its
// critical path is just dot(8-acc chain) -> shfl_xor(1) -> coef -> update.
// ---------------------------------------------------------------------------
__global__ __launch_bounds__(256, 1) void build_w_kernel(
    const float* __restrict__ vvec,     // [128][128], v_i = column i
    const float* __restrict__ scale_p,  // [1]
    const float* __restrict__ diag,     // [128]
    unsigned short* __restrict__ wt,    // [128][WT_STRIDE] bf16: wt[c][r] = W[r][c]
    float* __restrict__ logdet_out)
{
    __shared__ float vt[DIM * VT_STRIDE];   // vt[i*132 + j] = v_i[j]
    __shared__ float sc_lds[DIM];           // 1/(||v_i|| + eps)

    const int t  = threadIdx.x;
    const int r  = t >> 1;
    const int c0 = (t & 1) * 64;

    // load + transpose v_vectors (coalesced global read; one-time LDS write)
    for (int idx = t; idx < DIM * DIM; idx += 256) {
        int j = idx >> 7;      // row of vvec
        int i = idx & 127;     // col of vvec == step index
        vt[i * VT_STRIDE + j] = vvec[idx];
    }

    // Q = I  (compile-time indices only -> stays in VGPRs)
    float q[64];
    #pragma unroll
    for (int j = 0; j < 64; ++j) q[j] = (c0 + j == r) ? 1.0f : 0.0f;

    __syncthreads();

    // precompute all inverse norms: thread t (<128) owns column t
    if (t < DIM) {
        const float* v = &vt[t * VT_STRIDE];
        float s0 = 0.f, s1 = 0.f, s2 = 0.f, s3 = 0.f;
        #pragma unroll
        for (int k = 0; k < 32; ++k) {
            f32x4 w = *(const f32x4*)(v + 4 * k);
            s0 += w[0] * w[0]; s1 += w[1] * w[1];
            s2 += w[2] * w[2]; s3 += w[3] * w[3];
        }
        sc_lds[t] = 1.0f / (sqrtf((s0 + s1) + (s2 + s3)) + 1e-8f);
    }
    __syncthreads();

    for (int i = 0; i < DIM; ++i) {
        const float* __restrict__ v = &vt[i * VT_STRIDE];

        // this thread's 64 v elements -> registers (b128, 2 broadcast addrs
        // per instr, conflict-free); reused by dot and update
        float vv[64];
        #pragma unroll
        for (int k = 0; k < 16; ++k) {
            f32x4 w = *(const f32x4*)(v + c0 + 4 * k);
            vv[4*k]   = w[0]; vv[4*k+1] = w[1];
            vv[4*k+2] = w[2]; vv[4*k+3] = w[3];
        }

        // partial dot, 8 accumulators (serial FMA chain = 8 deep)
        float d0=0.f,d1=0.f,d2=0.f,d3=0.f,d4=0.f,d5=0.f,d6=0.f,d7=0.f;
        #pragma unroll
        for (int k = 0; k < 8; ++k) {
            d0 += q[8*k]   * vv[8*k];
            d1 += q[8*k+1] * vv[8*k+1];
            d2 += q[8*k+2] * vv[8*k+2];
            d3 += q[8*k+3] * vv[8*k+3];
            d4 += q[8*k+4] * vv[8*k+4];
            d5 += q[8*k+5] * vv[8*k+5];
            d6 += q[8*k+6] * vv[8*k+6];
            d7 += q[8*k+7] * vv[8*k+7];
        }
        float dot = ((d0+d1)+(d2+d3)) + ((d4+d5)+(d6+d7));
        dot += __shfl_xor(dot, 1, 64);   // lane pair (t, t^1) share row r

        const float sc   = sc_lds[i];
        const float coef = 2.0f * sc * sc * dot;
        #pragma unroll
        for (int j = 0; j < 64; ++j) q[j] -= coef * vv[j];
    }

    // W[r][c] = Q[r][c] * diag[c] * s ; store transposed bf16
    const float s = scale_p[0];
    #pragma unroll
    for (int j = 0; j < 64; ++j) {
        const int c = c0 + j;
        wt[c * WT_STRIDE + r] = f2bf(q[j] * diag[c] * s);
    }

    // logdet: wave 0 butterfly
    if (t < 64) {
        float ld = logf(fabsf(diag[t] * s) + 1e-8f)
                 + logf(fabsf(diag[t + 64] * s) + 1e-8f);
        #pragma unroll
        for (int m = 32; m >= 1; m >>= 1) ld += __shfl_xor(ld, m, 64);
        if (t == 0) *logdet_out = ld;
    }
}

// ---------------------------------------------------------------------------
// Kernel B: y = x @ W. Persistent: 1024 blocks (4/CU -> 16 waves/CU), each
// grid-strides 16 tiles of 64 rows (16 rows/wave). W^T staged to LDS once
// per block. Cross-tile register ping-pong (xa/xb, static indexing) keeps
// 8 dwordx4 in flight per wave under the current tile's MFMA + NT stores.
// VGPR budget: xa 32 + xb 32 + acc 32 + transients ~= 115 < 128 (4 w/SIMD).
// ---------------------------------------------------------------------------
__global__ __launch_bounds__(256, 4) void gemm_kernel(
    const float* __restrict__ x,
    const unsigned short* __restrict__ wt,
    float* __restrict__ y)
{
    __shared__ unsigned short wlds[DIM * WT_STRIDE];   // 34816 B

    const int t    = threadIdx.x;
    const int wave = t >> 6;
    const int lane = t & 63;
    const int n15  = lane & 15;
    const int quad = lane >> 4;

    // issue one tile's x loads into a register buffer (8 dwordx4 / wave)
    auto loadx = [&](f32x4 (&xb)[8], int tileIdx) {
        const long row = (long)tileIdx * ROWS_PER_TILE + wave * 16 + n15;
        const float* xrow = x + row * DIM + quad * 8;
        #pragma unroll
        for (int kc = 0; kc < 4; ++kc) {
            xb[kc * 2]     = *(const f32x4*)(xrow + kc * 32);
            xb[kc * 2 + 1] = *(const f32x4*)(xrow + kc * 32 + 4);
        }
    };

    // convert + 32 MFMA + NT-store one tile
    auto compute_store = [&](const f32x4 (&xb)[8], int tileIdx) {
        f32x4 acc[8];
        #pragma unroll
        for (int ct = 0; ct < 8; ++ct) acc[ct] = (f32x4)0.0f;

        #pragma unroll
        for (int kc = 0; kc < 4; ++kc) {
            const f32x4 lo = xb[kc * 2];
            const f32x4 hi = xb[kc * 2 + 1];
            bf16x8 f;
            f[0] = (short)f2bf(lo[0]); f[1] = (short)f2bf(lo[1]);
            f[2] = (short)f2bf(lo[2]); f[3] = (short)f2bf(lo[3]);
            f[4] = (short)f2bf(hi[0]); f[5] = (short)f2bf(hi[1]);
            f[6] = (short)f2bf(hi[2]); f[7] = (short)f2bf(hi[3]);
            const int koff = kc * 32 + quad * 8;
            #pragma unroll
            for (int ct = 0; ct < 8; ++ct) {
                const bf16x8 bfrag = *(const bf16x8*)&wlds[(ct * 16 + n15) * WT_STRIDE + koff];
                acc[ct] = __builtin_amdgcn_mfma_f32_16x16x32_bf16(f, bfrag, acc[ct], 0, 0, 0);
            }
        }

        // C/D layout: col = lane&15, row = quad*4 + reg. NT store (y is
        // write-once; keep it out of L2 so x streaming owns the cache).
        const long rowbase = (long)tileIdx * ROWS_PER_TILE + wave * 16;
        #pragma unroll
        for (int reg = 0; reg < 4; ++reg) {
            float* yrow = y + (rowbase + quad * 4 + reg) * DIM;
            #pragma unroll
            for (int ct = 0; ct < 8; ++ct) {
                __builtin_nontemporal_store(acc[ct][reg], &yrow[ct * 16 + n15]);
            }
        }
    };

    f32x4 xa[8], xb[8];

    loadx(xa, blockIdx.x);          // tile 0 loads fly under the LDS staging
    const int total4 = DIM * WT_STRIDE / 8;   // 2176
    for (int idx = t; idx < total4; idx += 256) {
        ((f32x4*)wlds)[idx] = ((const f32x4*)wt)[idx];
    }
    __syncthreads();                // wlds ready

    #pragma unroll 1
    for (int kk = 0; kk < TILES_PER_BLOCK / 2; ++kk) {
        const int t0 = blockIdx.x + (2 * kk) * GEMM_GRID;
        const int t1 = blockIdx.x + (2 * kk + 1) * GEMM_GRID;
        loadx(xb, t1);              // in flight under compute of t0
        compute_store(xa, t0);
        if (kk + 1 < TILES_PER_BLOCK / 2)
            loadx(xa, blockIdx.x + (2 * kk + 2) * GEMM_GRID);  // under compute of t1
        compute_store(xb, t1);
    }
}

extern "C" void kernel_launch(void* const* d_in, const int* in_sizes, int n_in,
                              void* d_out, int out_size, void* d_ws, size_t ws_size,
                              hipStream_t stream) {
    const float* x     = (const float*)d_in[0];
    const float* vvec  = (const float*)d_in[1];
    const float* scale = (const float*)d_in[2];
    const float* diag  = (const float*)d_in[3];

    float* y = (float*)d_out;
    float* logdet = y + (size_t)BATCH * DIM;        // outputs concatenated: y then logdet
    unsigned short* wt = (unsigned short*)d_ws;     // needs 128*136*2 = 34816 B

    build_w_kernel<<<1, 256, 0, stream>>>(vvec, scale, diag, wt, logdet);
    gemm_kernel<<<GEMM_GRID, 256, 0, stream>>>(x, wt, y);
}

// Round 3
// 916.790 us; speedup vs baseline: 1.2833x; 1.2833x over previous
//
#include <hip/hip_runtime.h>
#include <math.h>

#define DIM 128
#define BATCH 1048576
#define WT_STRIDE 136   // bf16 elements per row of W^T: 128 + 8 pad
#define VT_STRIDE 132   // f32 stride for staged v columns: %4==0 -> 16B-aligned b128 reads
#define GEMM_GRID 1024  // persistent grid
#define ROWS_PER_TILE 64                      // 4 waves x 16 rows
#define NTILES (BATCH / ROWS_PER_TILE)        // 16384
#define TILES_PER_BLOCK (NTILES / GEMM_GRID)  // 16 (even -> clean ping-pong)

typedef float f32x4 __attribute__((ext_vector_type(4)));
typedef short bf16x8 __attribute__((ext_vector_type(8)));

// fp32 -> bf16 round-to-nearest-even (bit trick; no NaN inputs here)
__device__ __forceinline__ unsigned short f2bf(float f) {
    unsigned u = __builtin_bit_cast(unsigned, f);
    u += 0x7FFFu + ((u >> 16) & 1u);
    return (unsigned short)(u >> 16);
}

// ---------------------------------------------------------------------------
// Kernel A: build W^T (bf16, padded stride) from the Householder scan.
// Pair-per-row layout: thread t holds Q[r][c0..c0+63], r = t>>1, c0=(t&1)*64.
// All 128 inverse norms precomputed before the scan -> the 128-step loop has
// zero barriers; critical path = dot(8-acc) -> shfl_xor(1) -> coef -> update.
// ---------------------------------------------------------------------------
__global__ __launch_bounds__(256, 1) void build_w_kernel(
    const float* __restrict__ vvec,     // [128][128], v_i = column i
    const float* __restrict__ scale_p,  // [1]
    const float* __restrict__ diag,     // [128]
    unsigned short* __restrict__ wt,    // [128][WT_STRIDE] bf16: wt[c][r] = W[r][c]
    float* __restrict__ logdet_out)
{
    __shared__ float vt[DIM * VT_STRIDE];   // vt[i*132 + j] = v_i[j]
    __shared__ float sc_lds[DIM];           // 1/(||v_i|| + eps)

    const int t  = threadIdx.x;
    const int r  = t >> 1;
    const int c0 = (t & 1) * 64;

    // load + transpose v_vectors (coalesced global read; one-time LDS write)
    for (int idx = t; idx < DIM * DIM; idx += 256) {
        int j = idx >> 7;      // row of vvec
        int i = idx & 127;     // col of vvec == step index
        vt[i * VT_STRIDE + j] = vvec[idx];
    }

    // Q = I  (compile-time indices only -> stays in VGPRs)
    float q[64];
    #pragma unroll
    for (int j = 0; j < 64; ++j) q[j] = (c0 + j == r) ? 1.0f : 0.0f;

    __syncthreads();

    // precompute all inverse norms: thread t (<128) owns column t
    if (t < DIM) {
        const float* v = &vt[t * VT_STRIDE];
        float s0 = 0.f, s1 = 0.f, s2 = 0.f, s3 = 0.f;
        #pragma unroll
        for (int k = 0; k < 32; ++k) {
            f32x4 w = *(const f32x4*)(v + 4 * k);
            s0 += w[0] * w[0]; s1 += w[1] * w[1];
            s2 += w[2] * w[2]; s3 += w[3] * w[3];
        }
        sc_lds[t] = 1.0f / (sqrtf((s0 + s1) + (s2 + s3)) + 1e-8f);
    }
    __syncthreads();

    for (int i = 0; i < DIM; ++i) {
        const float* __restrict__ v = &vt[i * VT_STRIDE];

        // this thread's 64 v elements -> registers (b128, 2 broadcast addrs
        // per instr, conflict-free); reused by dot and update
        float vv[64];
        #pragma unroll
        for (int k = 0; k < 16; ++k) {
            f32x4 w = *(const f32x4*)(v + c0 + 4 * k);
            vv[4*k]   = w[0]; vv[4*k+1] = w[1];
            vv[4*k+2] = w[2]; vv[4*k+3] = w[3];
        }

        // partial dot, 8 accumulators (serial FMA chain = 8 deep)
        float d0=0.f,d1=0.f,d2=0.f,d3=0.f,d4=0.f,d5=0.f,d6=0.f,d7=0.f;
        #pragma unroll
        for (int k = 0; k < 8; ++k) {
            d0 += q[8*k]   * vv[8*k];
            d1 += q[8*k+1] * vv[8*k+1];
            d2 += q[8*k+2] * vv[8*k+2];
            d3 += q[8*k+3] * vv[8*k+3];
            d4 += q[8*k+4] * vv[8*k+4];
            d5 += q[8*k+5] * vv[8*k+5];
            d6 += q[8*k+6] * vv[8*k+6];
            d7 += q[8*k+7] * vv[8*k+7];
        }
        float dot = ((d0+d1)+(d2+d3)) + ((d4+d5)+(d6+d7));
        dot += __shfl_xor(dot, 1, 64);   // lane pair (t, t^1) share row r

        const float sc   = sc_lds[i];
        const float coef = 2.0f * sc * sc * dot;
        #pragma unroll
        for (int j = 0; j < 64; ++j) q[j] -= coef * vv[j];
    }

    // W[r][c] = Q[r][c] * diag[c] * s ; store transposed bf16
    const float s = scale_p[0];
    #pragma unroll
    for (int j = 0; j < 64; ++j) {
        const int c = c0 + j;
        wt[c * WT_STRIDE + r] = f2bf(q[j] * diag[c] * s);
    }

    // logdet: wave 0 butterfly
    if (t < 64) {
        float ld = logf(fabsf(diag[t] * s) + 1e-8f)
                 + logf(fabsf(diag[t + 64] * s) + 1e-8f);
        #pragma unroll
        for (int m = 32; m >= 1; m >>= 1) ld += __shfl_xor(ld, m, 64);
        if (t == 0) *logdet_out = ld;
    }
}

// ---------------------------------------------------------------------------
// Kernel B: y = x @ W. Persistent: 1024 blocks, each grid-strides 16 tiles
// of 64 rows (16 rows/wave). W^T staged to LDS once per block. Cross-tile
// register ping-pong (xa/xb) keeps 8 dwordx4 in flight per wave under the
// current tile's MFMA + stores.
// __launch_bounds__(256,2): round-2's (256,4) squeeze made the compiler
// allocate only 64 VGPR and sink the prefetch loads (ping-pong needs
// xa32+xb32+acc32 ~ >=96 live). Plain stores: NT dword stores caused L2
// read-modify-write on 64B half-lines -> 2x HBM traffic (round-2 counters).
// ---------------------------------------------------------------------------
__global__ __launch_bounds__(256, 2) void gemm_kernel(
    const float* __restrict__ x,
    const unsigned short* __restrict__ wt,
    float* __restrict__ y)
{
    __shared__ unsigned short wlds[DIM * WT_STRIDE];   // 34816 B

    const int t    = threadIdx.x;
    const int wave = t >> 6;
    const int lane = t & 63;
    const int n15  = lane & 15;
    const int quad = lane >> 4;

    // issue one tile's x loads into a register buffer (8 dwordx4 / wave)
    auto loadx = [&](f32x4 (&xb)[8], int tileIdx) {
        const long row = (long)tileIdx * ROWS_PER_TILE + wave * 16 + n15;
        const float* xrow = x + row * DIM + quad * 8;
        #pragma unroll
        for (int kc = 0; kc < 4; ++kc) {
            xb[kc * 2]     = *(const f32x4*)(xrow + kc * 32);
            xb[kc * 2 + 1] = *(const f32x4*)(xrow + kc * 32 + 4);
        }
    };

    // convert + 32 MFMA + store one tile
    auto compute_store = [&](const f32x4 (&xb)[8], int tileIdx) {
        f32x4 acc[8];
        #pragma unroll
        for (int ct = 0; ct < 8; ++ct) acc[ct] = (f32x4)0.0f;

        #pragma unroll
        for (int kc = 0; kc < 4; ++kc) {
            const f32x4 lo = xb[kc * 2];
            const f32x4 hi = xb[kc * 2 + 1];
            bf16x8 f;
            f[0] = (short)f2bf(lo[0]); f[1] = (short)f2bf(lo[1]);
            f[2] = (short)f2bf(lo[2]); f[3] = (short)f2bf(lo[3]);
            f[4] = (short)f2bf(hi[0]); f[5] = (short)f2bf(hi[1]);
            f[6] = (short)f2bf(hi[2]); f[7] = (short)f2bf(hi[3]);
            const int koff = kc * 32 + quad * 8;
            #pragma unroll
            for (int ct = 0; ct < 8; ++ct) {
                const bf16x8 bfrag = *(const bf16x8*)&wlds[(ct * 16 + n15) * WT_STRIDE + koff];
                acc[ct] = __builtin_amdgcn_mfma_f32_16x16x32_bf16(f, bfrag, acc[ct], 0, 0, 0);
            }
        }

        // C/D layout: col = lane&15, row = quad*4 + reg. Plain dword stores:
        // each quad covers a contiguous 64B; L2 merges halves into full lines.
        const long rowbase = (long)tileIdx * ROWS_PER_TILE + wave * 16;
        #pragma unroll
        for (int reg = 0; reg < 4; ++reg) {
            float* yrow = y + (rowbase + quad * 4 + reg) * DIM;
            #pragma unroll
            for (int ct = 0; ct < 8; ++ct) {
                yrow[ct * 16 + n15] = acc[ct][reg];
            }
        }
    };

    f32x4 xa[8], xb[8];

    loadx(xa, blockIdx.x);          // tile 0 loads fly under the LDS staging
    const int total4 = DIM * WT_STRIDE / 8;   // 2176
    for (int idx = t; idx < total4; idx += 256) {
        ((f32x4*)wlds)[idx] = ((const f32x4*)wt)[idx];
    }
    __syncthreads();                // wlds ready

    #pragma unroll 1
    for (int kk = 0; kk < TILES_PER_BLOCK / 2; ++kk) {
        const int t0 = blockIdx.x + (2 * kk) * GEMM_GRID;
        const int t1 = blockIdx.x + (2 * kk + 1) * GEMM_GRID;
        loadx(xb, t1);              // in flight under compute of t0
        compute_store(xa, t0);
        if (kk + 1 < TILES_PER_BLOCK / 2)
            loadx(xa, blockIdx.x + (2 * kk + 2) * GEMM_GRID);  // under compute of t1
        compute_store(xb, t1);
    }
}

extern "C" void kernel_launch(void* const* d_in, const int* in_sizes, int n_in,
                              void* d_out, int out_size, void* d_ws, size_t ws_size,
                              hipStream_t stream) {
    const float* x     = (const float*)d_in[0];
    const float* vvec  = (const float*)d_in[1];
    const float* scale = (const float*)d_in[2];
    const float* diag  = (const float*)d_in[3];

    float* y = (float*)d_out;
    float* logdet = y + (size_t)BATCH * DIM;        // outputs concatenated: y then logdet
    unsigned short* wt = (unsigned short*)d_ws;     // needs 128*136*2 = 34816 B

    build_w_kernel<<<1, 256, 0, stream>>>(vvec, scale, diag, wt, logdet);
    gemm_kernel<<<GEMM_GRID, 256, 0, stream>>>(x, wt, y);
}